// Round 5
// baseline (113.959 us; speedup 1.0000x reference)
//
#include <hip/hip_runtime.h>

// GaussianBlur / upfirdn2d: 4x4 separable binomial [1,3,3,1] x [1,3,3,1] / 16,
// pad=(2,1), stride 1. In/out (8,128,256,256) fp32 NCHW. Memory-bound.
// One wave == one full row (64 lanes x float4 = W). Horizontal halos via __shfl,
// vertical conv via rolling 4-row register window, 2 independent strips per
// wave (MLP). This revision: PROBE — plain stores instead of nontemporal, to
// test whether the nt hint was impairing the write path. Everything else same.

typedef float fvec4 __attribute__((ext_vector_type(4)));

constexpr int H = 256;
constexpr int W = 256;
constexpr int RR = 32;               // output rows per strip
constexpr int STRIPS = H / RR;       // 8 strips per image
constexpr int NIMG = 8 * 128;        // N*C images
constexpr int TOTAL_STRIPS = NIMG * STRIPS;   // 8192
constexpr int HALF = TOTAL_STRIPS / 2;        // 4096

__global__ __launch_bounds__(256) void GaussianBlur_15358803050751_kernel(
        const float* __restrict__ in, float* __restrict__ out) {
    const int tid = threadIdx.x;
    const int qx = tid & 63;             // lane == float4 column (W/4 == 64)
    const int ty = tid >> 6;             // wave id within block

    const int s0 = blockIdx.x * 4 + ty;  // strip A (images 0..511)
    const int s1 = s0 + HALF;            // strip B (images 512..1023)

    const int imgA = s0 >> 3, sA = s0 & (STRIPS - 1), y0A = sA * RR;
    const int imgB = s1 >> 3, sB = s1 & (STRIPS - 1), y0B = sB * RR;

    const float* __restrict__ ipA = in  + (size_t)imgA * (H * W) + (qx << 2);
    float* __restrict__       opA = out + (size_t)imgA * (H * W) + (qx << 2);
    const float* __restrict__ ipB = in  + (size_t)imgB * (H * W) + (qx << 2);
    float* __restrict__       opB = out + (size_t)imgB * (H * W) + (qx << 2);

    // Horizontal conv [1,3,3,1]: neighbors via intra-wave shuffle.
    auto hconv = [&](fvec4 c) -> fvec4 {
        float lz = __shfl_up(c.z, 1, 64);    // row[x4-2] from lane qx-1
        float lw = __shfl_up(c.w, 1, 64);    // row[x4-1]
        float rx = __shfl_down(c.x, 1, 64);  // row[x4+4] from lane qx+1
        lz = (qx == 0)  ? 0.f : lz;          // image left zero-pad
        lw = (qx == 0)  ? 0.f : lw;
        rx = (qx == 63) ? 0.f : rx;          // image right zero-pad
        fvec4 h;
        h.x = lz  + 3.f * (lw  + c.x) + c.y;
        h.y = lw  + 3.f * (c.x + c.y) + c.z;
        h.z = c.x + 3.f * (c.y + c.z) + c.w;
        h.w = c.y + 3.f * (c.z + c.w) + rx;
        return h;
    };

    const fvec4 z4 = {0.f, 0.f, 0.f, 0.f};
    auto ld = [&](const float* p, int y) -> fvec4 {
        return *reinterpret_cast<const fvec4*>(p + (size_t)y * W);
    };

    // Rolling windows for both streams (input rows y-2, y-1, y).
    fvec4 haA = (y0A >= 2) ? hconv(ld(ipA, y0A - 2)) : z4;
    fvec4 haB = (y0B >= 2) ? hconv(ld(ipB, y0B - 2)) : z4;
    fvec4 hbA = (y0A >= 1) ? hconv(ld(ipA, y0A - 1)) : z4;
    fvec4 hbB = (y0B >= 1) ? hconv(ld(ipB, y0B - 1)) : z4;
    fvec4 hcA = hconv(ld(ipA, y0A));
    fvec4 hcB = hconv(ld(ipB, y0B));

    #pragma unroll 4
    for (int r = 0; r < RR; ++r) {
        const int yA = y0A + r;
        const int yB = y0B + r;
        // Issue both loads back-to-back (independent streams -> 2x MLP).
        const fvec4 cA = (yA + 1 < H) ? ld(ipA, yA + 1) : z4;
        const fvec4 cB = (yB + 1 < H) ? ld(ipB, yB + 1) : z4;
        const fvec4 hdA = hconv(cA);
        const fvec4 hdB = hconv(cB);
        fvec4 oA = (haA + 3.f * (hbA + hcA) + hdA) * 0.0625f;
        fvec4 oB = (haB + 3.f * (hbB + hcB) + hdB) * 0.0625f;
        // PROBE: plain (cached) stores this round — was __builtin_nontemporal_store.
        *reinterpret_cast<fvec4*>(opA + (size_t)yA * W) = oA;
        *reinterpret_cast<fvec4*>(opB + (size_t)yB * W) = oB;
        haA = hbA; hbA = hcA; hcA = hdA;
        haB = hbB; hbB = hcB; hcB = hdB;
    }
}

extern "C" void kernel_launch(void* const* d_in, const int* in_sizes, int n_in,
                              void* d_out, int out_size, void* d_ws, size_t ws_size,
                              hipStream_t stream) {
    (void)in_sizes; (void)n_in; (void)d_ws; (void)ws_size; (void)out_size;
    const float* in = (const float*)d_in[0];
    float* out = (float*)d_out;
    // 4096 first-half strips / 4 waves-per-block = 1024 blocks (each wave
    // also handles the matching second-half strip).
    const int blocks = HALF / 4;
    GaussianBlur_15358803050751_kernel<<<blocks, 256, 0, stream>>>(in, out);
}

// Round 6
// 84.710 us; speedup vs baseline: 1.3453x; 1.3453x over previous
//
#include <hip/hip_runtime.h>

// GaussianBlur / upfirdn2d: 4x4 separable binomial [1,3,3,1] x [1,3,3,1] / 16,
// pad=(2,1), stride 1. In/out (8,128,256,256) fp32 NCHW. Memory-bound.
// One wave == one full row (64 lanes x float4 = W). Horizontal halos via
// __shfl (zero extra memory traffic), vertical conv via rolling 4-row register
// window. Nontemporal stores are REQUIRED: cached stores evict input halo
// rows from L2 (+33% dur, measured R5). RR=64 minimizes vertical halo
// re-reads (67/64 = 4.7% read amplification).

typedef float fvec4 __attribute__((ext_vector_type(4)));

constexpr int H = 256;
constexpr int W = 256;
constexpr int RR = 64;               // output rows per wave-strip
constexpr int STRIPS = H / RR;       // 4 strips per image
constexpr int NIMG = 8 * 128;        // N*C images

__global__ __launch_bounds__(256) void GaussianBlur_15358803050751_kernel(
        const float* __restrict__ in, float* __restrict__ out) {
    const int tid = threadIdx.x;
    const int qx = tid & 63;             // lane == float4 column (W/4 == 64)
    const int ty = tid >> 6;             // wave id: 4 strips per block

    const int gstrip = blockIdx.x * 4 + ty;
    const int img = gstrip >> 2;         // / STRIPS
    const int s   = gstrip & (STRIPS - 1);
    const int y0  = s * RR;

    const float* __restrict__ ip = in  + (size_t)img * (H * W) + (qx << 2);
    float* __restrict__       op = out + (size_t)img * (H * W) + (qx << 2);

    // Horizontal conv [1,3,3,1]: neighbors via intra-wave shuffle.
    auto hconv = [&](fvec4 c) -> fvec4 {
        float lz = __shfl_up(c.z, 1, 64);    // row[x4-2] from lane qx-1
        float lw = __shfl_up(c.w, 1, 64);    // row[x4-1]
        float rx = __shfl_down(c.x, 1, 64);  // row[x4+4] from lane qx+1
        lz = (qx == 0)  ? 0.f : lz;          // image left zero-pad
        lw = (qx == 0)  ? 0.f : lw;
        rx = (qx == 63) ? 0.f : rx;          // image right zero-pad
        fvec4 h;
        h.x = lz  + 3.f * (lw  + c.x) + c.y;
        h.y = lw  + 3.f * (c.x + c.y) + c.z;
        h.z = c.x + 3.f * (c.y + c.z) + c.w;
        h.w = c.y + 3.f * (c.z + c.w) + rx;
        return h;
    };

    const fvec4 z4 = {0.f, 0.f, 0.f, 0.f};
    auto ld = [&](int y) -> fvec4 {
        return *reinterpret_cast<const fvec4*>(ip + (size_t)y * W);
    };

    // Rolling window: h of input rows y-2, y-1, y (zero rows above the image).
    fvec4 ha = (y0 >= 2) ? hconv(ld(y0 - 2)) : z4;
    fvec4 hb = (y0 >= 1) ? hconv(ld(y0 - 1)) : z4;
    fvec4 hc = hconv(ld(y0));

    #pragma unroll 8
    for (int r = 0; r < RR; ++r) {
        const int y = y0 + r;
        const fvec4 hd = (y + 1 < H) ? hconv(ld(y + 1)) : z4;
        fvec4 o = (ha + 3.f * (hb + hc) + hd) * 0.0625f;
        // Streaming output: nontemporal store keeps input halo rows in L2.
        __builtin_nontemporal_store(o, reinterpret_cast<fvec4*>(op + (size_t)y * W));
        ha = hb; hb = hc; hc = hd;
    }
}

extern "C" void kernel_launch(void* const* d_in, const int* in_sizes, int n_in,
                              void* d_out, int out_size, void* d_ws, size_t ws_size,
                              hipStream_t stream) {
    (void)in_sizes; (void)n_in; (void)d_ws; (void)ws_size; (void)out_size;
    const float* in = (const float*)d_in[0];
    float* out = (float*)d_out;
    // 1024 images * 4 strips / 4 strips-per-block = 1024 blocks
    const int blocks = NIMG * STRIPS / 4;
    GaussianBlur_15358803050751_kernel<<<blocks, 256, 0, stream>>>(in, out);
}